// Round 1
// baseline (55.206 us; speedup 1.0000x reference)
//
#include <hip/hip_runtime.h>
#include <math.h>

#define N_DIM 64
#define HT 64      // h per block
#define LT 64      // l per block
#define CHUNK 16   // l per thread (LT / 4 waves-worth of chunks)

__global__ __launch_bounds__(256) void dss_kernel(
    const float* __restrict__ log_dt,          // (H,2)
    const float* __restrict__ lam_log_neg_re,  // (N,)
    const float* __restrict__ lam_im,          // (N,)
    const float* __restrict__ W,               // (H,N,2)
    const int*   __restrict__ Lp,              // scalar
    float* __restrict__ out,                   // (L,H)
    int H)
{
    // params[n][h_local] = (a, b, Wk.re, Wk.im)
    __shared__ float4 params[N_DIM * HT];   // 64 KB

    const int tid = threadIdx.x;
    const int h0 = blockIdx.x * HT;
    const int l0_blk = blockIdx.y * LT;
    const int L = *Lp;

    const float2* __restrict__ W2 = (const float2*)W;

    // ---- Phase 1: build per-(h,n) params in LDS ----
    #pragma unroll
    for (int flat = tid; flat < N_DIM * HT; flat += 256) {
        const int hl = flat & (HT - 1);
        const int n  = flat >> 6;
        const int h  = h0 + hl;

        const float dt0 = expf(log_dt[2 * h]);
        const float dt1 = expf(log_dt[2 * h + 1]);
        const float lre = -expf(lam_log_neg_re[n]);
        const float lim = lam_im[n];

        const float a = dt0 * lre;   // Re(dt_Lambda)
        const float b = dt1 * lim;   // Im(dt_Lambda)

        // exp(dt_Lambda) - 1
        const float eA = expf(a);
        float sb, cb;
        sincosf(b, &sb, &cb);
        const float em1r = eA * cb - 1.0f;
        const float em1i = eA * sb;

        // reciprocal_clamped(Lam) = conj(Lam) / max(|Lam|^2, eps^2)
        const float den = fmaxf(lre * lre + lim * lim, 1e-14f);
        const float rr =  lre / den;
        const float ri = -lim / den;

        // Wk = Wc * (exp(dtL)-1) * recip(Lam)
        const float2 wc = W2[h * N_DIM + n];
        const float tr = em1r * rr - em1i * ri;
        const float ti = em1r * ri + em1i * rr;
        const float wkr = wc.x * tr - wc.y * ti;
        const float wki = wc.x * ti + wc.y * tr;

        params[flat] = make_float4(a, b, wkr, wki);
    }
    __syncthreads();

    // ---- Phase 2: each thread computes CHUNK consecutive l for one h ----
    const int hl = tid & (HT - 1);          // lane -> h (coalesced store)
    const int chunk = tid >> 6;             // wave index -> l chunk
    const int l0 = l0_blk + chunk * CHUNK;
    if (l0 >= L) return;

    float acc[CHUNK];
    #pragma unroll
    for (int k = 0; k < CHUNK; ++k) acc[k] = 0.0f;

    const double TWO_PI  = 6.283185307179586476925286766559;
    const double INV_2PI = 0.15915494309189533576888376337251;

    for (int n = 0; n < N_DIM; ++n) {
        const float4 p = params[n * HT + hl];
        const float a = p.x, b = p.y, wr = p.z, wi = p.w;

        // z = exp((a+ib)*l0): double-precision phase reduction mod 2*pi
        double ph = (double)b * (double)l0;
        ph -= TWO_PI * rint(ph * INV_2PI);
        const float th = (float)ph;
        const float e0 = expf(a * (float)l0);
        float s0, c0;
        sincosf(th, &s0, &c0);
        float zr = e0 * c0;
        float zi = e0 * s0;

        // step = exp(a+ib)
        const float eA = expf(a);
        float sb, cb;
        sincosf(b, &sb, &cb);
        const float str = eA * cb;
        const float sti = eA * sb;

        #pragma unroll
        for (int k = 0; k < CHUNK; ++k) {
            acc[k] = fmaf(wr, zr, fmaf(-wi, zi, acc[k]));
            const float nzr = zr * str - zi * sti;
            const float nzi = fmaf(zr, sti, zi * str);
            zr = nzr; zi = nzi;
        }
    }

    #pragma unroll
    for (int k = 0; k < CHUNK; ++k) {
        const int l = l0 + k;
        if (l < L) out[(size_t)l * H + h0 + hl] = acc[k];
    }
}

extern "C" void kernel_launch(void* const* d_in, const int* in_sizes, int n_in,
                              void* d_out, int out_size, void* d_ws, size_t ws_size,
                              hipStream_t stream) {
    const float* log_dt = (const float*)d_in[0];
    const float* llnr   = (const float*)d_in[1];
    const float* lim    = (const float*)d_in[2];
    const float* W      = (const float*)d_in[3];
    const int*   Lp     = (const int*)d_in[4];

    const int H = in_sizes[0] / 2;           // log_dt is (H,2)
    const int L_MAX = 2048;                  // bench L; kernel guards with *Lp

    dim3 grid(H / HT, L_MAX / LT);
    dim3 block(256);
    dss_kernel<<<grid, block, 0, stream>>>(log_dt, llnr, lim, W, Lp,
                                           (float*)d_out, H);
}

// Round 2
// 49.814 us; speedup vs baseline: 1.1082x; 1.1082x over previous
//
#include <hip/hip_runtime.h>
#include <math.h>

#define H_DIM 1024
#define N_DIM 64
#define L_MAX 2048
#define CHUNK 16
#define LT 64                 // l per block (4 chunk-waves of 16)
#define JMAX (L_MAX / LT)     // 32
#define NH (N_DIM * H_DIM)    // 65536

// ---------------- fast path ----------------

__device__ __forceinline__ float2 cmul(float2 a, float2 b) {
    return make_float2(a.x * b.x - a.y * b.y, a.x * b.y + a.y * b.x);
}

// ws float2 layout: zbig[JMAX][N][H] | wk[N][H] | step[N][H] | spow[3][N][H]
__global__ __launch_bounds__(256) void dss_setup(
    const float* __restrict__ log_dt,
    const float* __restrict__ llnr,
    const float* __restrict__ lim,
    const float* __restrict__ W,
    float2* __restrict__ ws)
{
    const int flat = blockIdx.x * 256 + threadIdx.x;   // 65536 threads
    if (flat >= NH) return;
    const int h = flat & (H_DIM - 1);
    const int n = flat >> 10;

    const float dt0 = expf(log_dt[2 * h]);
    const float dt1 = expf(log_dt[2 * h + 1]);
    const float lre = -expf(llnr[n]);
    const float lmi = lim[n];
    const float a = dt0 * lre;
    const float b = dt1 * lmi;

    float sb, cb;
    sincosf(b, &sb, &cb);
    const float eA = expf(a);
    const float2 st = make_float2(eA * cb, eA * sb);     // exp(dt_Lambda)

    // Wk = Wc * (exp(dtL)-1) * conj(Lam)/max(|Lam|^2, eps^2)
    const float den = fmaxf(lre * lre + lmi * lmi, 1e-14f);
    const float rr = lre / den, ri = -lmi / den;
    const float em1r = st.x - 1.0f, em1i = st.y;
    const float2 wc = ((const float2*)W)[h * N_DIM + n];
    const float tr = em1r * rr - em1i * ri;
    const float ti = em1r * ri + em1i * rr;
    const float2 wk = make_float2(wc.x * tr - wc.y * ti, wc.x * ti + wc.y * tr);

    // powers of step
    const float2 s2  = cmul(st,  st);
    const float2 s4  = cmul(s2,  s2);
    const float2 s8  = cmul(s4,  s4);
    const float2 s16 = cmul(s8,  s8);
    const float2 s32 = cmul(s16, s16);
    const float2 s48 = cmul(s32, s16);
    const float2 s64 = cmul(s32, s32);

    const int idx = n * H_DIM + h;
    float2* zbig = ws;
    float2* wkA  = ws + (size_t)JMAX * NH;
    float2* stA  = wkA + NH;
    float2* spA  = stA + NH;

    wkA[idx] = wk;
    stA[idx] = st;
    spA[0 * NH + idx] = s16;
    spA[1 * NH + idx] = s32;
    spA[2 * NH + idx] = s48;

    float2 z = make_float2(1.0f, 0.0f);
    zbig[idx] = z;
    for (int j = 1; j < JMAX; ++j) {
        z = cmul(z, s64);
        zbig[(size_t)j * NH + idx] = z;
    }
}

__global__ __launch_bounds__(256) void dss_main(
    const float2* __restrict__ ws,
    const int* __restrict__ Lp,
    float* __restrict__ out)
{
    const float2* zbig = ws;
    const float2* wkA  = ws + (size_t)JMAX * NH;
    const float2* stA  = wkA + NH;
    const float2* spA  = stA + NH;

    const int tid   = threadIdx.x;
    const int j     = blockIdx.x & (JMAX - 1);      // l-block of 64
    const int htile = blockIdx.x >> 5;              // 16 tiles of 64 h
    const int hl    = tid & 63;
    const int chunk = tid >> 6;                     // 0..3, wave-uniform
    const int h     = htile * 64 + hl;
    const int l0    = j * LT + chunk * CHUNK;
    const int L     = *Lp;
    if (l0 >= L) return;

    float acc[CHUNK];
    #pragma unroll
    for (int k = 0; k < CHUNK; ++k) acc[k] = 0.0f;

    const size_t jbase = (size_t)j * NH;
    const int spoff = (chunk - 1) * NH;   // only used when chunk>0

    int idx = h;
    float2 wk_c = wkA[idx];
    float2 st_c = stA[idx];
    float2 zb_c = zbig[jbase + idx];
    float2 sp_c = (chunk > 0) ? spA[spoff + idx] : make_float2(1.0f, 0.0f);

    for (int n = 0; n < N_DIM; ++n) {
        const float2 wk = wk_c, st = st_c, zb = zb_c, sp = sp_c;
        if (n + 1 < N_DIM) {
            const int idx2 = idx + H_DIM;
            wk_c = wkA[idx2];
            st_c = stA[idx2];
            zb_c = zbig[jbase + idx2];
            sp_c = (chunk > 0) ? spA[spoff + idx2] : make_float2(1.0f, 0.0f);
        }
        idx += H_DIM;

        float zr = zb.x * sp.x - zb.y * sp.y;
        float zi = zb.x * sp.y + zb.y * sp.x;

        #pragma unroll
        for (int k = 0; k < CHUNK; ++k) {
            acc[k] = fmaf(wk.x, zr, fmaf(-wk.y, zi, acc[k]));
            const float nzr = fmaf(zr, st.x, -(zi * st.y));
            const float nzi = fmaf(zr, st.y,   zi * st.x);
            zr = nzr; zi = nzi;
        }
    }

    #pragma unroll
    for (int k = 0; k < CHUNK; ++k) {
        const int l = l0 + k;
        if (l < L) out[(size_t)l * H_DIM + h] = acc[k];
    }
}

// ---------------- fallback (round-1 proven kernel) ----------------

#define HT 64

__global__ __launch_bounds__(256) void dss_kernel_fb(
    const float* __restrict__ log_dt,
    const float* __restrict__ lam_log_neg_re,
    const float* __restrict__ lam_im,
    const float* __restrict__ W,
    const int*   __restrict__ Lp,
    float* __restrict__ out,
    int H)
{
    __shared__ float4 params[N_DIM * HT];
    const int tid = threadIdx.x;
    const int h0 = blockIdx.x * HT;
    const int l0_blk = blockIdx.y * 64;
    const int L = *Lp;
    const float2* __restrict__ W2 = (const float2*)W;

    #pragma unroll
    for (int flat = tid; flat < N_DIM * HT; flat += 256) {
        const int hl = flat & (HT - 1);
        const int n  = flat >> 6;
        const int h  = h0 + hl;
        const float dt0 = expf(log_dt[2 * h]);
        const float dt1 = expf(log_dt[2 * h + 1]);
        const float lre = -expf(lam_log_neg_re[n]);
        const float lmi = lam_im[n];
        const float a = dt0 * lre;
        const float b = dt1 * lmi;
        const float eA = expf(a);
        float sb, cb;
        sincosf(b, &sb, &cb);
        const float em1r = eA * cb - 1.0f;
        const float em1i = eA * sb;
        const float den = fmaxf(lre * lre + lmi * lmi, 1e-14f);
        const float rr =  lre / den;
        const float ri = -lmi / den;
        const float2 wc = W2[h * N_DIM + n];
        const float tr = em1r * rr - em1i * ri;
        const float ti = em1r * ri + em1i * rr;
        const float wkr = wc.x * tr - wc.y * ti;
        const float wki = wc.x * ti + wc.y * tr;
        params[flat] = make_float4(a, b, wkr, wki);
    }
    __syncthreads();

    const int hl = tid & (HT - 1);
    const int chunk = tid >> 6;
    const int l0 = l0_blk + chunk * CHUNK;
    if (l0 >= L) return;

    float acc[CHUNK];
    #pragma unroll
    for (int k = 0; k < CHUNK; ++k) acc[k] = 0.0f;

    const double TWO_PI  = 6.283185307179586476925286766559;
    const double INV_2PI = 0.15915494309189533576888376337251;

    for (int n = 0; n < N_DIM; ++n) {
        const float4 p = params[n * HT + hl];
        const float a = p.x, b = p.y, wr = p.z, wi = p.w;
        double ph = (double)b * (double)l0;
        ph -= TWO_PI * rint(ph * INV_2PI);
        const float th = (float)ph;
        const float e0 = expf(a * (float)l0);
        float s0, c0;
        sincosf(th, &s0, &c0);
        float zr = e0 * c0;
        float zi = e0 * s0;
        const float eA = expf(a);
        float sb, cb;
        sincosf(b, &sb, &cb);
        const float str = eA * cb;
        const float sti = eA * sb;
        #pragma unroll
        for (int k = 0; k < CHUNK; ++k) {
            acc[k] = fmaf(wr, zr, fmaf(-wi, zi, acc[k]));
            const float nzr = zr * str - zi * sti;
            const float nzi = fmaf(zr, sti, zi * str);
            zr = nzr; zi = nzi;
        }
    }

    #pragma unroll
    for (int k = 0; k < CHUNK; ++k) {
        const int l = l0 + k;
        if (l < L) out[(size_t)l * H + h0 + hl] = acc[k];
    }
}

// ---------------- launch ----------------

extern "C" void kernel_launch(void* const* d_in, const int* in_sizes, int n_in,
                              void* d_out, int out_size, void* d_ws, size_t ws_size,
                              hipStream_t stream) {
    const float* log_dt = (const float*)d_in[0];
    const float* llnr   = (const float*)d_in[1];
    const float* lim    = (const float*)d_in[2];
    const float* W      = (const float*)d_in[3];
    const int*   Lp     = (const int*)d_in[4];

    const int H = in_sizes[0] / 2;
    const size_t ws_needed = (size_t)(JMAX * NH + 2 * NH + 3 * NH) * sizeof(float2); // ~19.4 MB

    if (H == H_DIM && in_sizes[1] == N_DIM && ws_size >= ws_needed) {
        float2* ws = (float2*)d_ws;
        dss_setup<<<NH / 256, 256, 0, stream>>>(log_dt, llnr, lim, W, ws);
        dss_main<<<(H_DIM / 64) * JMAX, 256, 0, stream>>>(ws, Lp, (float*)d_out);
    } else {
        dim3 grid(H / HT, L_MAX / 64);
        dss_kernel_fb<<<grid, 256, 0, stream>>>(log_dt, llnr, lim, W, Lp,
                                                (float*)d_out, H);
    }
}

// Round 3
// 33.410 us; speedup vs baseline: 1.6524x; 1.4910x over previous
//
#include <hip/hip_runtime.h>
#include <math.h>

#define H_DIM 1024
#define N_DIM 64
#define L_MAX 2048
#define LPW   512           // l per wave
#define GRP   64            // l per group (= lane count)
#define NGRP  (LPW / GRP)   // 8
#define NW    4             // waves per block (4 consecutive h)

__device__ __forceinline__ float2 cmul(float2 a, float2 b) {
    return make_float2(fmaf(a.x, b.x, -(a.y * b.y)),
                       fmaf(a.x, b.y,   a.y * b.x));
}

// ---------------- main kernel: wave = one h, lane = n ----------------

__global__ __launch_bounds__(256) void dss_wave(
    const float* __restrict__ log_dt,   // (H,2)
    const float* __restrict__ llnr,     // (N,)
    const float* __restrict__ limv,     // (N,)
    const float* __restrict__ W,        // (H,N,2)
    const int*   __restrict__ Lp,
    float* __restrict__ out)            // (L,H)
{
    __shared__ float lds_t[GRP * (NW + 1)];   // padded stride 5 -> <=3-way banks

    const int tid   = threadIdx.x;
    const int lane  = tid & 63;
    const int w     = tid >> 6;           // 0..3
    const int htile = blockIdx.x;         // 0..255
    const int lseg  = blockIdx.y;         // 0..(L/512-1), block-uniform
    const int h     = htile * NW + w;
    const int L     = *Lp;

    // ---- per-lane (h, n) setup: the only transcendentals in the kernel ----
    const float dt0 = expf(log_dt[2 * h]);
    const float dt1 = expf(log_dt[2 * h + 1]);
    const float lre = -expf(llnr[lane]);
    const float lmi = limv[lane];
    const float a = dt0 * lre;
    const float b = dt1 * lmi;

    float sb, cb;
    sincosf(b, &sb, &cb);
    const float eA = expf(a);
    const float2 st = make_float2(eA * cb, eA * sb);    // exp(dt_Lambda)

    // Wk = Wc * (exp(dtL)-1) * conj(Lam)/max(|Lam|^2, eps^2)
    const float den = fmaxf(lre * lre + lmi * lmi, 1e-14f);
    const float rr = lre / den, ri = -lmi / den;
    const float em1r = st.x - 1.0f, em1i = st.y;
    const float2 wc = ((const float2*)W)[h * N_DIM + lane];
    const float tr = em1r * rr - em1i * ri;
    const float ti = em1r * ri + em1i * rr;
    const float2 wk = make_float2(wc.x * tr - wc.y * ti,
                                  wc.x * ti + wc.y * tr);

    // powers of st: s64 (group advance) and s512 (segment start)
    const float2 s2   = cmul(st, st);
    const float2 s4   = cmul(s2, s2);
    const float2 s8   = cmul(s4, s4);
    const float2 s16  = cmul(s8, s8);
    const float2 s32  = cmul(s16, s16);
    const float2 s64  = cmul(s32, s32);
    const float2 s128 = cmul(s64, s64);
    const float2 s256 = cmul(s128, s128);
    const float2 s512 = cmul(s256, s256);

    float2 z = make_float2(1.0f, 0.0f);        // st^(lseg*512)
    for (int i = 0; i < lseg; ++i) z = cmul(z, s512);

    // 2nd-order real recurrence coefficients: roots {st, conj(st)}
    const float p = 2.0f * st.x;
    const float q = -(eA * eA);                // -|st|^2

    #pragma unroll 1
    for (int g = 0; g < NGRP; ++g) {
        const int lbase = lseg * LPW + g * GRP;
        if (lbase >= L) break;                 // block-uniform exit

        float v[GRP];
        float t0 = fmaf(wk.x, z.x, -(wk.y * z.y));     // Re(wk * st^lbase)
        const float2 z1 = cmul(z, st);
        float t1 = fmaf(wk.x, z1.x, -(wk.y * z1.y));
        v[0] = t0; v[1] = t1;
        #pragma unroll
        for (int k = 2; k < GRP; ++k) {
            const float t2 = fmaf(p, t1, q * t0);
            v[k] = t2;
            t0 = t1; t1 = t2;
        }
        z = cmul(z, s64);                      // start of next group

        // butterfly transpose-reduce: lane i ends with sum_n for l=lbase+i
        #pragma unroll
        for (int s = 0; s < 6; ++s) {
            const int d = 1 << s;
            const bool hi = (lane & d) != 0;
            #pragma unroll
            for (int k = 0; k < (GRP >> s); k += 2) {
                const float give = hi ? v[k]     : v[k + 1];
                const float keep = hi ? v[k + 1] : v[k];
                const float got  = __shfl_xor(give, d, 64);
                v[k >> 1] = keep + got;
            }
        }

        // coalesce stores via cross-wave LDS transpose (4 h per block)
        __syncthreads();
        lds_t[lane * (NW + 1) + w] = v[0];
        __syncthreads();
        const int r = tid >> 2, c = tid & 3;
        const int l = lbase + r;
        if (l < L) out[(size_t)l * H_DIM + htile * NW + c] = lds_t[r * (NW + 1) + c];
    }
}

// ---------------- fallback (round-1 proven kernel) ----------------

#define HT 64
#define CHUNK 16

__global__ __launch_bounds__(256) void dss_kernel_fb(
    const float* __restrict__ log_dt,
    const float* __restrict__ lam_log_neg_re,
    const float* __restrict__ lam_im,
    const float* __restrict__ W,
    const int*   __restrict__ Lp,
    float* __restrict__ out,
    int H, int N)
{
    __shared__ float4 params[N_DIM * HT];
    const int tid = threadIdx.x;
    const int h0 = blockIdx.x * HT;
    const int l0_blk = blockIdx.y * 64;
    const int L = *Lp;
    const float2* __restrict__ W2 = (const float2*)W;

    for (int flat = tid; flat < N * HT; flat += 256) {
        const int hl = flat & (HT - 1);
        const int n  = flat >> 6;
        const int h  = h0 + hl;
        const float dt0 = expf(log_dt[2 * h]);
        const float dt1 = expf(log_dt[2 * h + 1]);
        const float lre = -expf(lam_log_neg_re[n]);
        const float lmi = lam_im[n];
        const float a = dt0 * lre;
        const float b = dt1 * lmi;
        const float eA = expf(a);
        float sb, cb;
        sincosf(b, &sb, &cb);
        const float em1r = eA * cb - 1.0f;
        const float em1i = eA * sb;
        const float den = fmaxf(lre * lre + lmi * lmi, 1e-14f);
        const float rr =  lre / den;
        const float ri = -lmi / den;
        const float2 wc = W2[h * N + n];
        const float trm = em1r * rr - em1i * ri;
        const float tim = em1r * ri + em1i * rr;
        params[flat] = make_float4(a, b,
                                   wc.x * trm - wc.y * tim,
                                   wc.x * tim + wc.y * trm);
    }
    __syncthreads();

    const int hl = tid & (HT - 1);
    const int chunk = tid >> 6;
    const int l0 = l0_blk + chunk * CHUNK;
    if (l0 >= L) return;

    float acc[CHUNK];
    #pragma unroll
    for (int k = 0; k < CHUNK; ++k) acc[k] = 0.0f;

    const double TWO_PI  = 6.283185307179586476925286766559;
    const double INV_2PI = 0.15915494309189533576888376337251;

    for (int n = 0; n < N; ++n) {
        const float4 pp = params[n * HT + hl];
        const float a = pp.x, b = pp.y, wr = pp.z, wi = pp.w;
        double ph = (double)b * (double)l0;
        ph -= TWO_PI * rint(ph * INV_2PI);
        const float th = (float)ph;
        const float e0 = expf(a * (float)l0);
        float s0, c0;
        sincosf(th, &s0, &c0);
        float zr = e0 * c0;
        float zi = e0 * s0;
        const float eA = expf(a);
        float sb, cb;
        sincosf(b, &sb, &cb);
        const float str = eA * cb;
        const float sti = eA * sb;
        #pragma unroll
        for (int k = 0; k < CHUNK; ++k) {
            acc[k] = fmaf(wr, zr, fmaf(-wi, zi, acc[k]));
            const float nzr = zr * str - zi * sti;
            const float nzi = fmaf(zr, sti, zi * str);
            zr = nzr; zi = nzi;
        }
    }

    #pragma unroll
    for (int k = 0; k < CHUNK; ++k) {
        const int l = l0 + k;
        if (l < L) out[(size_t)l * H + h0 + hl] = acc[k];
    }
}

// ---------------- launch ----------------

extern "C" void kernel_launch(void* const* d_in, const int* in_sizes, int n_in,
                              void* d_out, int out_size, void* d_ws, size_t ws_size,
                              hipStream_t stream) {
    const float* log_dt = (const float*)d_in[0];
    const float* llnr   = (const float*)d_in[1];
    const float* lim    = (const float*)d_in[2];
    const float* W      = (const float*)d_in[3];
    const int*   Lp     = (const int*)d_in[4];

    const int H = in_sizes[0] / 2;
    const int N = in_sizes[1];
    const int L = out_size / (H > 0 ? H : 1);

    if (H == H_DIM && N == N_DIM) {
        const int lsegs = (L + LPW - 1) / LPW;
        dim3 grid(H_DIM / NW, lsegs);
        dss_wave<<<grid, 256, 0, stream>>>(log_dt, llnr, lim, W, Lp, (float*)d_out);
    } else {
        dim3 grid((H + HT - 1) / HT, (L + 63) / 64);
        dss_kernel_fb<<<grid, 256, 0, stream>>>(log_dt, llnr, lim, W, Lp,
                                                (float*)d_out, H, N);
    }
}

// Round 4
// 27.217 us; speedup vs baseline: 2.0284x; 1.2276x over previous
//
#include <hip/hip_runtime.h>
#include <math.h>

#define H_DIM 1024
#define N_DIM 64
#define BH 16          // h per block
#define BL 128         // l per block
#define KL 8           // l per thread (stride 16)
#define NB 16          // n per batch
#define NBATCH (N_DIM / NB)
#define TROW 33        // padded row (32 chain values + 1 pad)

__device__ __forceinline__ float2 cmul(float2 a, float2 b) {
    return make_float2(fmaf(a.x, b.x, -(a.y * b.y)),
                       fmaf(a.x, b.y,   a.y * b.x));
}

// ---------------- main kernel: thread = (h, c); lane-coalesced over h ----------------
// out[l0 + c + 16k, h0 + h] for k = 0..7, accumulated over all n.
// Per batch of NB n: 256 threads each build one (h,n) start-chain in LDS,
// then every thread consumes all NB rows for its h via stride-16 recurrence.

__global__ __launch_bounds__(256) void dss_chunk(
    const float* __restrict__ log_dt,   // (H,2)
    const float* __restrict__ llnr,     // (N,)
    const float* __restrict__ limv,     // (N,)
    const float* __restrict__ W,        // (H,N,2)
    const int*   __restrict__ Lp,
    float* __restrict__ out)            // (L,H)
{
    __shared__ float  tbl[NB * BH * TROW];   // 33.8 KB
    __shared__ float2 pqs[NB * BH];          // 2 KB

    const int tid = threadIdx.x;
    const int h   = tid >> 4;        // 0..15 (lane bits 4..5 -> 4 h per wave)
    const int sub = tid & 15;        // build: n_local; main: c
    const int h0  = blockIdx.x * BH;
    const int l0  = blockIdx.y * BL;
    const int L   = *Lp;

    // per-thread h constants (reused all batches)
    const float dt0 = expf(log_dt[2 * (h0 + h)]);
    const float dt1 = expf(log_dt[2 * (h0 + h) + 1]);

    // reader offsets for the 4 swizzle classes (statically indexed by nl&3)
    int ofa[4], ofb[4];
    #pragma unroll
    for (int m = 0; m < 4; ++m) {
        const int sw = ((h ^ m) & 3) << 3;
        ofa[m] = sub ^ sw;
        ofb[m] = (sub + 16) ^ sw;
    }

    float acc[KL];
    #pragma unroll
    for (int k = 0; k < KL; ++k) acc[k] = 0.0f;

    for (int bt = 0; bt < NBATCH; ++bt) {
        __syncthreads();   // previous batch's readers done before overwrite
        {   // ---- build: this thread owns (h, n = bt*NB + sub) ----
            const int nl = sub;
            const int n  = bt * NB + nl;
            const float lre = -expf(llnr[n]);
            const float lmi = limv[n];
            const float a = dt0 * lre;
            const float b = dt1 * lmi;
            float sb, cb;
            sincosf(b, &sb, &cb);
            const float eA = expf(a);
            const float2 s = make_float2(eA * cb, eA * sb);   // exp(dt_Lambda)

            // Wk = Wc * (exp(dtL)-1) * conj(Lam)/max(|Lam|^2, eps^2)
            const float den = fmaxf(lre * lre + lmi * lmi, 1e-14f);
            const float rr = lre / den, ri = -lmi / den;
            const float em1r = s.x - 1.0f, em1i = s.y;
            const float2 wc = ((const float2*)W)[(size_t)(h0 + h) * N_DIM + n];
            const float tr = em1r * rr - em1i * ri;
            const float ti = em1r * ri + em1i * rr;
            const float wkr = wc.x * tr - wc.y * ti;
            const float wki = wc.x * ti + wc.y * tr;

            // 1-step recurrence coeffs (roots {s, conj s})
            const float p1 = 2.0f * s.x;
            const float q1 = -(eA * eA);

            // s^16 -> stride-16 coeffs for the main loop
            const float2 s2 = cmul(s, s), s4 = cmul(s2, s2);
            const float2 s8 = cmul(s4, s4), s16 = cmul(s8, s8);
            pqs[nl * BH + h] =
                make_float2(2.0f * s16.x, -(s16.x * s16.x + s16.y * s16.y));

            // z = s^{l0} via s^128 square-multiply (block-uniform exponent)
            const float2 s32 = cmul(s16, s16), s64 = cmul(s32, s32), s128 = cmul(s64, s64);
            float2 z = make_float2(1.0f, 0.0f);
            float2 pw = s128;
            int e = blockIdx.y;
            while (e) { if (e & 1) z = cmul(z, pw); pw = cmul(pw, pw); e >>= 1; }

            // w0 = wk * s^{l0}; chain t(l0+j), j=0..31
            const float w0r = wkr * z.x - wki * z.y;
            const float w0i = wkr * z.y + wki * z.x;

            float* row = &tbl[(nl * BH + h) * TROW];
            const int sw = ((h ^ nl) & 3) << 3;
            float t0 = w0r;                       // Re(wk s^l0)
            float t1 = w0r * s.x - w0i * s.y;     // Re(wk s^(l0+1))
            row[0 ^ sw] = t0;
            row[1 ^ sw] = t1;
            #pragma unroll
            for (int j = 2; j < 32; ++j) {
                const float t2 = fmaf(p1, t1, q1 * t0);
                row[j ^ sw] = t2;
                t0 = t1; t1 = t2;
            }
        }
        __syncthreads();

        // ---- main: consume all NB rows for this thread's h ----
        const float* rowh = &tbl[h * TROW];
        #pragma unroll
        for (int nl = 0; nl < NB; ++nl) {
            const float* row = rowh + nl * (BH * TROW);
            float ta = row[ofa[nl & 3]];          // t(l0 + c)
            float tb = row[ofb[nl & 3]];          // t(l0 + c + 16)
            const float2 pq = pqs[nl * BH + h];
            acc[0] += ta;
            acc[1] += tb;
            #pragma unroll
            for (int k = 2; k < KL; ++k) {
                const float tc = fmaf(pq.x, tb, pq.y * ta);
                acc[k] += tc;
                ta = tb; tb = tc;
            }
        }
    }

    // ---- epilogue: LDS transpose (reuse tbl) -> fully coalesced 64B stores ----
    __syncthreads();
    #pragma unroll
    for (int k = 0; k < KL; ++k)
        tbl[(sub + 16 * k) * BH + h] = acc[k];
    __syncthreads();
    #pragma unroll
    for (int i = 0; i < 8; ++i) {
        const int flat = i * 256 + tid;
        const int ll = flat >> 4, hh = flat & 15;
        const int l = l0 + ll;
        if (l < L) out[(size_t)l * H_DIM + h0 + hh] = tbl[flat];
    }
}

// ---------------- generic fallback (round-1 proven structure) ----------------

#define HT 64
#define CHUNK 16

__global__ __launch_bounds__(256) void dss_kernel_fb(
    const float* __restrict__ log_dt,
    const float* __restrict__ lam_log_neg_re,
    const float* __restrict__ lam_im,
    const float* __restrict__ W,
    const int*   __restrict__ Lp,
    float* __restrict__ out,
    int H, int N)
{
    __shared__ float4 params[N_DIM * HT];
    const int tid = threadIdx.x;
    const int h0 = blockIdx.x * HT;
    const int l0_blk = blockIdx.y * 64;
    const int L = *Lp;
    const float2* __restrict__ W2 = (const float2*)W;

    for (int flat = tid; flat < N * HT; flat += 256) {
        const int hl = flat & (HT - 1);
        const int n  = flat >> 6;
        const int h  = h0 + hl;
        const float dt0 = expf(log_dt[2 * h]);
        const float dt1 = expf(log_dt[2 * h + 1]);
        const float lre = -expf(lam_log_neg_re[n]);
        const float lmi = lam_im[n];
        const float a = dt0 * lre;
        const float b = dt1 * lmi;
        const float eA = expf(a);
        float sb, cb;
        sincosf(b, &sb, &cb);
        const float em1r = eA * cb - 1.0f;
        const float em1i = eA * sb;
        const float den = fmaxf(lre * lre + lmi * lmi, 1e-14f);
        const float rr =  lre / den;
        const float ri = -lmi / den;
        const float2 wc = W2[h * N + n];
        const float trm = em1r * rr - em1i * ri;
        const float tim = em1r * ri + em1i * rr;
        params[flat] = make_float4(a, b,
                                   wc.x * trm - wc.y * tim,
                                   wc.x * tim + wc.y * trm);
    }
    __syncthreads();

    const int hl = tid & (HT - 1);
    const int chunk = tid >> 6;
    const int l0 = l0_blk + chunk * CHUNK;
    if (l0 >= L) return;

    float acc[CHUNK];
    #pragma unroll
    for (int k = 0; k < CHUNK; ++k) acc[k] = 0.0f;

    const double TWO_PI  = 6.283185307179586476925286766559;
    const double INV_2PI = 0.15915494309189533576888376337251;

    for (int n = 0; n < N; ++n) {
        const float4 pp = params[n * HT + hl];
        const float a = pp.x, b = pp.y, wr = pp.z, wi = pp.w;
        double ph = (double)b * (double)l0;
        ph -= TWO_PI * rint(ph * INV_2PI);
        const float th = (float)ph;
        const float e0 = expf(a * (float)l0);
        float s0, c0;
        sincosf(th, &s0, &c0);
        float zr = e0 * c0;
        float zi = e0 * s0;
        const float eA = expf(a);
        float sb, cb;
        sincosf(b, &sb, &cb);
        const float str = eA * cb;
        const float sti = eA * sb;
        #pragma unroll
        for (int k = 0; k < CHUNK; ++k) {
            acc[k] = fmaf(wr, zr, fmaf(-wi, zi, acc[k]));
            const float nzr = zr * str - zi * sti;
            const float nzi = fmaf(zr, sti, zi * str);
            zr = nzr; zi = nzi;
        }
    }

    #pragma unroll
    for (int k = 0; k < CHUNK; ++k) {
        const int l = l0 + k;
        if (l < L) out[(size_t)l * H + h0 + hl] = acc[k];
    }
}

// ---------------- launch ----------------

extern "C" void kernel_launch(void* const* d_in, const int* in_sizes, int n_in,
                              void* d_out, int out_size, void* d_ws, size_t ws_size,
                              hipStream_t stream) {
    const float* log_dt = (const float*)d_in[0];
    const float* llnr   = (const float*)d_in[1];
    const float* lim    = (const float*)d_in[2];
    const float* W      = (const float*)d_in[3];
    const int*   Lp     = (const int*)d_in[4];

    const int H = in_sizes[0] / 2;
    const int N = in_sizes[1];
    const int L = out_size / (H > 0 ? H : 1);

    if (H == H_DIM && N == N_DIM) {
        dim3 grid(H_DIM / BH, (L + BL - 1) / BL);   // 64 x 16 = 1024 blocks
        dss_chunk<<<grid, 256, 0, stream>>>(log_dt, llnr, lim, W, Lp, (float*)d_out);
    } else {
        dim3 grid((H + HT - 1) / HT, (L + 63) / 64);
        dss_kernel_fb<<<grid, 256, 0, stream>>>(log_dt, llnr, lim, W, Lp,
                                                (float*)d_out, H, N);
    }
}

// Round 5
// 26.106 us; speedup vs baseline: 2.1147x; 1.0426x over previous
//
#include <hip/hip_runtime.h>
#include <math.h>

#define H_DIM 1024
#define N_DIM 64
#define BH 16          // h per block
#define BL 128         // l per block
#define KL 8           // l per thread (stride 16)
#define NB 16          // n per batch
#define NBATCH (N_DIM / NB)
#define TROW 33        // padded row (32 chain values + 1 pad)
#define LSEG_MAX 16
#define NH (N_DIM * H_DIM)

__device__ __forceinline__ float2 cmul(float2 a, float2 b) {
    return make_float2(fmaf(a.x, b.x, -(a.y * b.y)),
                       fmaf(a.x, b.y,   a.y * b.x));
}

// ---------------- prep: all transcendentals, once per (h,n) ----------------
// ws float2 layout: starts[LSEG_MAX][N][H] | s[N][H] | pq16[N][H]

__global__ __launch_bounds__(256) void dss_prep(
    const float* __restrict__ log_dt,   // (H,2)
    const float* __restrict__ llnr,     // (N,)
    const float* __restrict__ limv,     // (N,)
    const float* __restrict__ W,        // (H,N,2)
    float2* __restrict__ ws)
{
    const int flat = blockIdx.x * 256 + threadIdx.x;   // 65536 threads
    const int n = flat >> 10;
    const int h = flat & (H_DIM - 1);

    const float dt0 = expf(log_dt[2 * h]);
    const float dt1 = expf(log_dt[2 * h + 1]);
    const float lre = -expf(llnr[n]);
    const float lmi = limv[n];
    const float a = dt0 * lre;
    const float b = dt1 * lmi;

    float sb, cb;
    sincosf(b, &sb, &cb);
    const float eA = expf(a);
    const float2 s = make_float2(eA * cb, eA * sb);    // exp(dt_Lambda)

    // Wk = Wc * (exp(dtL)-1) * conj(Lam)/max(|Lam|^2, eps^2)
    const float den = fmaxf(lre * lre + lmi * lmi, 1e-14f);
    const float rr = lre / den, ri = -lmi / den;
    const float em1r = s.x - 1.0f, em1i = s.y;
    const float2 wc = ((const float2*)W)[(size_t)h * N_DIM + n];
    const float tr = em1r * rr - em1i * ri;
    const float ti = em1r * ri + em1i * rr;
    const float2 wk = make_float2(wc.x * tr - wc.y * ti,
                                  wc.x * ti + wc.y * tr);

    const float2 s2 = cmul(s, s), s4 = cmul(s2, s2);
    const float2 s8 = cmul(s4, s4), s16 = cmul(s8, s8);
    const float2 s32 = cmul(s16, s16), s64 = cmul(s32, s32);
    const float2 s128 = cmul(s64, s64);

    float2* starts = ws;
    float2* sarr   = ws + (size_t)LSEG_MAX * NH;
    float2* pqarr  = sarr + NH;

    const int idx = n * H_DIM + h;                 // consecutive h = coalesced
    sarr[idx]  = s;
    pqarr[idx] = make_float2(2.0f * s16.x,
                             -(fmaf(s16.x, s16.x, s16.y * s16.y)));

    const float2 P0 = s128, P1 = cmul(P0, P0), P2 = cmul(P1, P1), P3 = cmul(P2, P2);
    #pragma unroll
    for (int g = 0; g < LSEG_MAX; ++g) {
        float2 z = make_float2(1.0f, 0.0f);
        if (g & 1) z = cmul(z, P0);
        if (g & 2) z = cmul(z, P1);
        if (g & 4) z = cmul(z, P2);
        if (g & 8) z = cmul(z, P3);
        starts[(size_t)g * NH + idx] = cmul(wk, z); // Wk * s^(128*g)
    }
}

// ---------------- main: no transcendentals, LDS chain table ----------------

__global__ __launch_bounds__(256, 4) void dss_main2(
    const float2* __restrict__ ws,
    const int* __restrict__ Lp,
    float* __restrict__ out)
{
    __shared__ float  tbl[NB * BH * TROW];   // 33.8 KB
    __shared__ float2 pqs[NB * BH];          // 2 KB

    const float2* starts = ws;
    const float2* sarr   = ws + (size_t)LSEG_MAX * NH;
    const float2* pqarr  = sarr + NH;

    const int tid  = threadIdx.x;
    const int h0   = blockIdx.x * BH;
    const int lseg = blockIdx.y;
    const int l0   = lseg * BL;
    const int L    = *Lp;

    // build mapping: lane-consecutive h -> coalesced param loads
    const int bh = tid & 15, bn = tid >> 4;

    // prefetch ALL batch params up front (statically indexed: loop unrolled)
    float2 w0v[NBATCH], sv[NBATCH], pqv[NBATCH];
    #pragma unroll
    for (int bt = 0; bt < NBATCH; ++bt) {
        const int idx = (bt * NB + bn) * H_DIM + h0 + bh;
        w0v[bt] = starts[(size_t)lseg * NH + idx];
        sv[bt]  = sarr[idx];
        pqv[bt] = pqarr[idx];
    }

    // main mapping + swizzled read offsets (precomputed, statically indexed)
    const int h = tid >> 4, sub = tid & 15;
    int ofa[4], ofb[4];
    #pragma unroll
    for (int m = 0; m < 4; ++m) {
        const int sw = ((h ^ m) & 3) << 3;
        ofa[m] = sub ^ sw;
        ofb[m] = (sub + 16) ^ sw;
    }

    float acc[KL];
    #pragma unroll
    for (int k = 0; k < KL; ++k) acc[k] = 0.0f;

    #pragma unroll
    for (int bt = 0; bt < NBATCH; ++bt) {
        __syncthreads();   // previous batch's readers done before overwrite
        {   // ---- build: thread owns (bh, n = bt*NB + bn); 2 FMA/value ----
            const float2 w0 = w0v[bt], s = sv[bt];
            const float p1 = 2.0f * s.x;
            const float q1 = -(fmaf(s.x, s.x, s.y * s.y));
            float* row = &tbl[(bn * BH + bh) * TROW];
            const int sw = ((bh ^ bn) & 3) << 3;
            float t0 = w0.x;                           // Re(wk s^l0)
            float t1 = w0.x * s.x - w0.y * s.y;        // Re(wk s^(l0+1))
            row[0 ^ sw] = t0;
            row[1 ^ sw] = t1;
            #pragma unroll
            for (int j = 2; j < 32; ++j) {
                const float t2 = fmaf(p1, t1, q1 * t0);
                row[j ^ sw] = t2;
                t0 = t1; t1 = t2;
            }
            pqs[bn * BH + bh] = pqv[bt];
        }
        __syncthreads();

        // ---- main: runtime outer x2, unrolled inner x8 (static swz idx) ----
        const float* rowh = &tbl[h * TROW];
        for (int g = 0; g < 2; ++g) {
            const float*  rowg = rowh + (g * 8) * (BH * TROW);
            const float2* pqg  = &pqs[(g * 8) * BH + h];
            #pragma unroll
            for (int j = 0; j < 8; ++j) {
                const float* row = rowg + j * (BH * TROW);
                float ta = row[ofa[j & 3]];            // t(l0 + c)
                float tb = row[ofb[j & 3]];            // t(l0 + c + 16)
                const float2 pq = pqg[j * BH];
                acc[0] += ta;
                acc[1] += tb;
                #pragma unroll
                for (int k = 2; k < KL; ++k) {
                    const float tc = fmaf(pq.x, tb, pq.y * ta);
                    acc[k] += tc;
                    ta = tb; tb = tc;
                }
            }
        }
    }

    // ---- epilogue: LDS transpose (reuse tbl) -> coalesced 64B stores ----
    __syncthreads();
    #pragma unroll
    for (int k = 0; k < KL; ++k)
        tbl[(sub + 16 * k) * BH + h] = acc[k];
    __syncthreads();
    #pragma unroll
    for (int i = 0; i < 8; ++i) {
        const int flat = i * 256 + tid;
        const int ll = flat >> 4, hh = flat & 15;
        const int l = l0 + ll;
        if (l < L) out[(size_t)l * H_DIM + h0 + hh] = tbl[flat];
    }
}

// ---------------- generic fallback (round-1 proven structure) ----------------

#define HT 64
#define CHUNK 16

__global__ __launch_bounds__(256) void dss_kernel_fb(
    const float* __restrict__ log_dt,
    const float* __restrict__ lam_log_neg_re,
    const float* __restrict__ lam_im,
    const float* __restrict__ W,
    const int*   __restrict__ Lp,
    float* __restrict__ out,
    int H, int N)
{
    __shared__ float4 params[N_DIM * HT];
    const int tid = threadIdx.x;
    const int h0 = blockIdx.x * HT;
    const int l0_blk = blockIdx.y * 64;
    const int L = *Lp;
    const float2* __restrict__ W2 = (const float2*)W;

    for (int flat = tid; flat < N * HT; flat += 256) {
        const int hl = flat & (HT - 1);
        const int n  = flat >> 6;
        const int h  = h0 + hl;
        const float dt0 = expf(log_dt[2 * h]);
        const float dt1 = expf(log_dt[2 * h + 1]);
        const float lre = -expf(lam_log_neg_re[n]);
        const float lmi = lam_im[n];
        const float a = dt0 * lre;
        const float b = dt1 * lmi;
        const float eA = expf(a);
        float sb, cb;
        sincosf(b, &sb, &cb);
        const float em1r = eA * cb - 1.0f;
        const float em1i = eA * sb;
        const float den = fmaxf(lre * lre + lmi * lmi, 1e-14f);
        const float rr =  lre / den;
        const float ri = -lmi / den;
        const float2 wc = W2[h * N + n];
        const float trm = em1r * rr - em1i * ri;
        const float tim = em1r * ri + em1i * rr;
        params[flat] = make_float4(a, b,
                                   wc.x * trm - wc.y * tim,
                                   wc.x * tim + wc.y * trm);
    }
    __syncthreads();

    const int hl = tid & (HT - 1);
    const int chunk = tid >> 6;
    const int l0 = l0_blk + chunk * CHUNK;
    if (l0 >= L) return;

    float acc[CHUNK];
    #pragma unroll
    for (int k = 0; k < CHUNK; ++k) acc[k] = 0.0f;

    const double TWO_PI  = 6.283185307179586476925286766559;
    const double INV_2PI = 0.15915494309189533576888376337251;

    for (int n = 0; n < N; ++n) {
        const float4 pp = params[n * HT + hl];
        const float a = pp.x, b = pp.y, wr = pp.z, wi = pp.w;
        double ph = (double)b * (double)l0;
        ph -= TWO_PI * rint(ph * INV_2PI);
        const float th = (float)ph;
        const float e0 = expf(a * (float)l0);
        float s0, c0;
        sincosf(th, &s0, &c0);
        float zr = e0 * c0;
        float zi = e0 * s0;
        const float eA = expf(a);
        float sb, cb;
        sincosf(b, &sb, &cb);
        const float str = eA * cb;
        const float sti = eA * sb;
        #pragma unroll
        for (int k = 0; k < CHUNK; ++k) {
            acc[k] = fmaf(wr, zr, fmaf(-wi, zi, acc[k]));
            const float nzr = zr * str - zi * sti;
            const float nzi = fmaf(zr, sti, zi * str);
            zr = nzr; zi = nzi;
        }
    }

    #pragma unroll
    for (int k = 0; k < CHUNK; ++k) {
        const int l = l0 + k;
        if (l < L) out[(size_t)l * H + h0 + hl] = acc[k];
    }
}

// ---------------- launch ----------------

extern "C" void kernel_launch(void* const* d_in, const int* in_sizes, int n_in,
                              void* d_out, int out_size, void* d_ws, size_t ws_size,
                              hipStream_t stream) {
    const float* log_dt = (const float*)d_in[0];
    const float* llnr   = (const float*)d_in[1];
    const float* lim    = (const float*)d_in[2];
    const float* W      = (const float*)d_in[3];
    const int*   Lp     = (const int*)d_in[4];

    const int H = in_sizes[0] / 2;
    const int N = in_sizes[1];
    const int L = out_size / (H > 0 ? H : 1);

    const size_t ws_needed = (size_t)(LSEG_MAX + 2) * NH * sizeof(float2); // 9.4 MB

    if (H == H_DIM && N == N_DIM && L <= LSEG_MAX * BL && ws_size >= ws_needed) {
        float2* ws = (float2*)d_ws;
        dss_prep<<<NH / 256, 256, 0, stream>>>(log_dt, llnr, lim, W, ws);
        dim3 grid(H_DIM / BH, (L + BL - 1) / BL);
        dss_main2<<<grid, 256, 0, stream>>>(ws, Lp, (float*)d_out);
    } else {
        dim3 grid((H + HT - 1) / HT, (L + 63) / 64);
        dss_kernel_fb<<<grid, 256, 0, stream>>>(log_dt, llnr, lim, W, Lp,
                                                (float*)d_out, H, N);
    }
}

// Round 6
// 25.410 us; speedup vs baseline: 2.1726x; 1.0274x over previous
//
#include <hip/hip_runtime.h>
#include <math.h>

#define H_DIM 1024
#define N_DIM 64
#define BH 16          // h per block
#define BL 128         // l per block
#define KL 8           // l per thread (stride 16)
#define NB 16          // n per batch
#define NBATCH (N_DIM / NB)
#define LSEG_MAX 16
#define NH (N_DIM * H_DIM)

__device__ __forceinline__ float2 cmul(float2 a, float2 b) {
    return make_float2(fmaf(a.x, b.x, -(a.y * b.y)),
                       fmaf(a.x, b.y,   a.y * b.x));
}

// ---------------- prep: all transcendentals, once per (h,n) ----------------
// ws float2 layout: starts[LSEG_MAX][N][H] | s[N][H] | pq16[N][H]

__global__ __launch_bounds__(256) void dss_prep(
    const float* __restrict__ log_dt,   // (H,2)
    const float* __restrict__ llnr,     // (N,)
    const float* __restrict__ limv,     // (N,)
    const float* __restrict__ W,        // (H,N,2)
    float2* __restrict__ ws)
{
    const int flat = blockIdx.x * 256 + threadIdx.x;   // 65536 threads
    const int n = flat >> 10;
    const int h = flat & (H_DIM - 1);

    const float dt0 = expf(log_dt[2 * h]);
    const float dt1 = expf(log_dt[2 * h + 1]);
    const float lre = -expf(llnr[n]);
    const float lmi = limv[n];
    const float a = dt0 * lre;
    const float b = dt1 * lmi;

    float sb, cb;
    sincosf(b, &sb, &cb);
    const float eA = expf(a);
    const float2 s = make_float2(eA * cb, eA * sb);    // exp(dt_Lambda)

    // Wk = Wc * (exp(dtL)-1) * conj(Lam)/max(|Lam|^2, eps^2)
    const float den = fmaxf(lre * lre + lmi * lmi, 1e-14f);
    const float rr = lre / den, ri = -lmi / den;
    const float em1r = s.x - 1.0f, em1i = s.y;
    const float2 wc = ((const float2*)W)[(size_t)h * N_DIM + n];
    const float tr = em1r * rr - em1i * ri;
    const float ti = em1r * ri + em1i * rr;
    const float2 wk = make_float2(wc.x * tr - wc.y * ti,
                                  wc.x * ti + wc.y * tr);

    const float2 s2 = cmul(s, s), s4 = cmul(s2, s2);
    const float2 s8 = cmul(s4, s4), s16 = cmul(s8, s8);
    const float2 s32 = cmul(s16, s16), s64 = cmul(s32, s32);
    const float2 s128 = cmul(s64, s64);

    float2* starts = ws;
    float2* sarr   = ws + (size_t)LSEG_MAX * NH;
    float2* pqarr  = sarr + NH;

    const int idx = n * H_DIM + h;                 // consecutive h = coalesced
    sarr[idx]  = s;
    pqarr[idx] = make_float2(2.0f * s16.x,
                             -(fmaf(s16.x, s16.x, s16.y * s16.y)));

    const float2 P0 = s128, P1 = cmul(P0, P0), P2 = cmul(P1, P1), P3 = cmul(P2, P2);
    #pragma unroll
    for (int g = 0; g < LSEG_MAX; ++g) {
        float2 z = make_float2(1.0f, 0.0f);
        if (g & 1) z = cmul(z, P0);
        if (g & 2) z = cmul(z, P1);
        if (g & 4) z = cmul(z, P2);
        if (g & 8) z = cmul(z, P3);
        starts[(size_t)g * NH + idx] = cmul(wk, z); // Wk * s^(128*g)
    }
}

// ---------------- main: pair-vectorized LDS chain table ----------------
// tblp row (n,h): 16 float2 pairs, pair c at pos (c ^ h): (t(l0+c), t(l0+c+16))

__global__ __launch_bounds__(256, 4) void dss_main3(
    const float2* __restrict__ ws,
    const int* __restrict__ Lp,
    float* __restrict__ out)
{
    __shared__ float2 tblp[NB * BH * 16];    // 32 KB
    __shared__ float2 pqs[NB * BH];          // 2 KB

    const float2* starts = ws;
    const float2* sarr   = ws + (size_t)LSEG_MAX * NH;
    const float2* pqarr  = sarr + NH;

    const int tid  = threadIdx.x;
    const int h0   = blockIdx.x * BH;
    const int lseg = blockIdx.y;
    const int l0   = lseg * BL;
    const int L    = *Lp;

    // build mapping: lane-consecutive h -> coalesced param loads
    const int bh = tid & 15, bn = tid >> 4;

    // prefetch ALL batch params up front (statically indexed: loop unrolled)
    float2 w0v[NBATCH], sv[NBATCH], pqv[NBATCH];
    #pragma unroll
    for (int bt = 0; bt < NBATCH; ++bt) {
        const int idx = (bt * NB + bn) * H_DIM + h0 + bh;
        w0v[bt] = starts[(size_t)lseg * NH + idx];
        sv[bt]  = sarr[idx];
        pqv[bt] = pqarr[idx];
    }

    // main mapping
    const int h = tid >> 4, sub = tid & 15;
    const int rdoff = sub ^ h;               // swizzled pair position

    float acc[KL];
    #pragma unroll
    for (int k = 0; k < KL; ++k) acc[k] = 0.0f;

    #pragma unroll
    for (int bt = 0; bt < NBATCH; ++bt) {
        __syncthreads();   // previous batch's readers done before overwrite
        {   // ---- build: thread owns (bh, n = bt*NB + bn) ----
            const float2 w0 = w0v[bt], s = sv[bt];
            const float p1 = 2.0f * s.x;
            const float q1 = -(fmaf(s.x, s.x, s.y * s.y));
            float t[32];
            t[0] = w0.x;                                // Re(wk s^l0)
            t[1] = fmaf(w0.x, s.x, -(w0.y * s.y));      // Re(wk s^(l0+1))
            #pragma unroll
            for (int j = 2; j < 32; ++j)
                t[j] = fmaf(p1, t[j - 1], q1 * t[j - 2]);

            float2* row = &tblp[(bn * BH + bh) * 16];
            #pragma unroll
            for (int p = 0; p < 16; ++p)
                row[p ^ bh] = make_float2(t[p], t[p + 16]);  // 16x ds_write_b64
            pqs[bn * BH + bh] = pqv[bt];
        }
        __syncthreads();

        // ---- main: one ds_read_b64 per n gives (ta, tb) seed ----
        const float2* rowh = &tblp[h * 16 + rdoff];
        #pragma unroll
        for (int nl = 0; nl < NB; ++nl) {
            const float2 tab = rowh[nl * (BH * 16)];
            const float2 pq  = pqs[nl * BH + h];
            float ta = tab.x, tb = tab.y;
            acc[0] += ta;
            acc[1] += tb;
            #pragma unroll
            for (int k = 2; k < KL; ++k) {
                const float tc = fmaf(pq.x, tb, pq.y * ta);
                acc[k] += tc;
                ta = tb; tb = tc;
            }
        }
    }

    // ---- epilogue: LDS transpose -> float4 coalesced stores ----
    __syncthreads();
    float* scr = (float*)tblp;               // [128 l][16 h] floats = 8 KB
    #pragma unroll
    for (int k = 0; k < KL; ++k)
        scr[(sub + 16 * k) * BH + h] = acc[k];
    __syncthreads();
    const float4* scr4 = (const float4*)scr;
    float4* out4 = (float4*)out;
    #pragma unroll
    for (int i = 0; i < 2; ++i) {
        const int flat = i * 256 + tid;      // float4 index: 128 l x 4
        const int ll = flat >> 2, q = flat & 3;
        const int l = l0 + ll;
        if (l < L) out4[(size_t)l * (H_DIM / 4) + (h0 >> 2) + q] = scr4[flat];
    }
}

// ---------------- generic fallback (round-1 proven structure) ----------------

#define HT 64
#define CHUNK 16

__global__ __launch_bounds__(256) void dss_kernel_fb(
    const float* __restrict__ log_dt,
    const float* __restrict__ lam_log_neg_re,
    const float* __restrict__ lam_im,
    const float* __restrict__ W,
    const int*   __restrict__ Lp,
    float* __restrict__ out,
    int H, int N)
{
    __shared__ float4 params[N_DIM * HT];
    const int tid = threadIdx.x;
    const int h0 = blockIdx.x * HT;
    const int l0_blk = blockIdx.y * 64;
    const int L = *Lp;
    const float2* __restrict__ W2 = (const float2*)W;

    for (int flat = tid; flat < N * HT; flat += 256) {
        const int hl = flat & (HT - 1);
        const int n  = flat >> 6;
        const int h  = h0 + hl;
        const float dt0 = expf(log_dt[2 * h]);
        const float dt1 = expf(log_dt[2 * h + 1]);
        const float lre = -expf(lam_log_neg_re[n]);
        const float lmi = lam_im[n];
        const float a = dt0 * lre;
        const float b = dt1 * lmi;
        const float eA = expf(a);
        float sb, cb;
        sincosf(b, &sb, &cb);
        const float em1r = eA * cb - 1.0f;
        const float em1i = eA * sb;
        const float den = fmaxf(lre * lre + lmi * lmi, 1e-14f);
        const float rr =  lre / den;
        const float ri = -lmi / den;
        const float2 wc = W2[h * N + n];
        const float trm = em1r * rr - em1i * ri;
        const float tim = em1r * ri + em1i * rr;
        params[flat] = make_float4(a, b,
                                   wc.x * trm - wc.y * tim,
                                   wc.x * tim + wc.y * trm);
    }
    __syncthreads();

    const int hl = tid & (HT - 1);
    const int chunk = tid >> 6;
    const int l0 = l0_blk + chunk * CHUNK;
    if (l0 >= L) return;

    float acc[CHUNK];
    #pragma unroll
    for (int k = 0; k < CHUNK; ++k) acc[k] = 0.0f;

    const double TWO_PI  = 6.283185307179586476925286766559;
    const double INV_2PI = 0.15915494309189533576888376337251;

    for (int n = 0; n < N; ++n) {
        const float4 pp = params[n * HT + hl];
        const float a = pp.x, b = pp.y, wr = pp.z, wi = pp.w;
        double ph = (double)b * (double)l0;
        ph -= TWO_PI * rint(ph * INV_2PI);
        const float th = (float)ph;
        const float e0 = expf(a * (float)l0);
        float s0, c0;
        sincosf(th, &s0, &c0);
        float zr = e0 * c0;
        float zi = e0 * s0;
        const float eA = expf(a);
        float sb, cb;
        sincosf(b, &sb, &cb);
        const float str = eA * cb;
        const float sti = eA * sb;
        #pragma unroll
        for (int k = 0; k < CHUNK; ++k) {
            acc[k] = fmaf(wr, zr, fmaf(-wi, zi, acc[k]));
            const float nzr = zr * str - zi * sti;
            const float nzi = fmaf(zr, sti, zi * str);
            zr = nzr; zi = nzi;
        }
    }

    #pragma unroll
    for (int k = 0; k < CHUNK; ++k) {
        const int l = l0 + k;
        if (l < L) out[(size_t)l * H + h0 + hl] = acc[k];
    }
}

// ---------------- launch ----------------

extern "C" void kernel_launch(void* const* d_in, const int* in_sizes, int n_in,
                              void* d_out, int out_size, void* d_ws, size_t ws_size,
                              hipStream_t stream) {
    const float* log_dt = (const float*)d_in[0];
    const float* llnr   = (const float*)d_in[1];
    const float* lim    = (const float*)d_in[2];
    const float* W      = (const float*)d_in[3];
    const int*   Lp     = (const int*)d_in[4];

    const int H = in_sizes[0] / 2;
    const int N = in_sizes[1];
    const int L = out_size / (H > 0 ? H : 1);

    const size_t ws_needed = (size_t)(LSEG_MAX + 2) * NH * sizeof(float2); // 9.4 MB

    if (H == H_DIM && N == N_DIM && L <= LSEG_MAX * BL && ws_size >= ws_needed) {
        float2* ws = (float2*)d_ws;
        dss_prep<<<NH / 256, 256, 0, stream>>>(log_dt, llnr, lim, W, ws);
        dim3 grid(H_DIM / BH, (L + BL - 1) / BL);
        dss_main3<<<grid, 256, 0, stream>>>(ws, Lp, (float*)d_out);
    } else {
        dim3 grid((H + HT - 1) / HT, (L + 63) / 64);
        dss_kernel_fb<<<grid, 256, 0, stream>>>(log_dt, llnr, lim, W, Lp,
                                                (float*)d_out, H, N);
    }
}

// Round 8
// 25.092 us; speedup vs baseline: 2.2001x; 1.0126x over previous
//
#include <hip/hip_runtime.h>
#include <math.h>

#define H_DIM 1024
#define N_DIM 64
#define BH 16          // h per block
#define BL 128         // l per segment
#define KL 8           // l per thread (stride 16)
#define NB 16          // n per batch
#define NBATCH (N_DIM / NB)   // 4
#define LPB 2          // l-segments per block

__device__ __forceinline__ float2 cmul(float2 a, float2 b) {
    return make_float2(fmaf(a.x, b.x, -(a.y * b.y)),
                       fmaf(a.x, b.y,   a.y * b.x));
}

// ---------------- fused: params in registers, pair-vectorized LDS table ----------------
// tblp row (n,h): 16 float2 pairs, pair c at pos (c ^ h): (t(l0+c), t(l0+c+16))

__global__ __launch_bounds__(256, 2) void dss_fused(
    const float* __restrict__ log_dt,   // (H,2)
    const float* __restrict__ llnr,     // (N,)
    const float* __restrict__ limv,     // (N,)
    const float* __restrict__ W,        // (H,N,2)
    const int*   __restrict__ Lp,
    float* __restrict__ out)            // (L,H)
{
    __shared__ float2 tblp[NB * BH * 16];    // 32 KB
    __shared__ float2 pqs[NB * BH];          // 2 KB

    const int tid = threadIdx.x;
    const int h0  = blockIdx.x * BH;
    const int g   = blockIdx.y;              // l-segment pair index
    const int L   = *Lp;

    const int bh = tid & 15, bn = tid >> 4;  // builder mapping

    // ---- per-thread param build (NBATCH sets), all in registers ----
    const float dt0 = expf(log_dt[2 * (h0 + bh)]);
    const float dt1 = expf(log_dt[2 * (h0 + bh) + 1]);

    float2 sv[NBATCH], pqv[NBATCH], w0v[NBATCH], s128v[NBATCH];
    #pragma unroll
    for (int bt = 0; bt < NBATCH; ++bt) {
        const int n = bt * NB + bn;
        const float lre = -expf(llnr[n]);
        const float lmi = limv[n];
        const float a = dt0 * lre;
        const float b = dt1 * lmi;
        float sb, cb;
        sincosf(b, &sb, &cb);
        const float eA = expf(a);
        const float2 s = make_float2(eA * cb, eA * sb);   // exp(dt_Lambda)
        sv[bt] = s;

        // Wk = Wc * (exp(dtL)-1) * conj(Lam)/max(|Lam|^2, eps^2)
        const float den = fmaxf(lre * lre + lmi * lmi, 1e-14f);
        const float rr = lre / den, ri = -lmi / den;
        const float em1r = s.x - 1.0f, em1i = s.y;
        const float2 wc = ((const float2*)W)[(size_t)(h0 + bh) * N_DIM + n];
        const float tr = em1r * rr - em1i * ri;
        const float ti = em1r * ri + em1i * rr;
        const float2 wk = make_float2(wc.x * tr - wc.y * ti,
                                      wc.x * ti + wc.y * tr);

        const float2 s2 = cmul(s, s), s4 = cmul(s2, s2);
        const float2 s8 = cmul(s4, s4), s16 = cmul(s8, s8);
        pqv[bt] = make_float2(2.0f * s16.x,
                              -(fmaf(s16.x, s16.x, s16.y * s16.y)));
        const float2 s32 = cmul(s16, s16), s64 = cmul(s32, s32);
        const float2 s128 = cmul(s64, s64);
        s128v[bt] = s128;

        // w0 = wk * s^(128 * (LPB*g)) = wk * (s^256)^g   (g <= 7)
        const float2 s256  = cmul(s128, s128);
        const float2 s512  = cmul(s256, s256);
        const float2 s1024 = cmul(s512, s512);
        float2 z = wk;
        if (g & 1) z = cmul(z, s256);
        if (g & 2) z = cmul(z, s512);
        if (g & 4) z = cmul(z, s1024);
        w0v[bt] = z;
    }

    // consumer mapping
    const int h = tid >> 4, sub = tid & 15;
    const int rdoff = sub ^ h;               // swizzled pair position

    #pragma unroll
    for (int ls = 0; ls < LPB; ++ls) {
        const int lseg = g * LPB + ls;
        const int l0 = lseg * BL;
        if (l0 < L) {                        // block-uniform
            float acc[KL];
            #pragma unroll
            for (int k = 0; k < KL; ++k) acc[k] = 0.0f;

            #pragma unroll
            for (int bt = 0; bt < NBATCH; ++bt) {
                __syncthreads();   // previous phase's readers done before overwrite
                {   // ---- build: thread owns (bh, n = bt*NB + bn) ----
                    const float2 w0 = w0v[bt], s = sv[bt];
                    const float p1 = 2.0f * s.x;
                    const float q1 = -(fmaf(s.x, s.x, s.y * s.y));
                    float t[32];
                    t[0] = w0.x;                                // Re(wk s^l0)
                    t[1] = fmaf(w0.x, s.x, -(w0.y * s.y));      // Re(wk s^(l0+1))
                    #pragma unroll
                    for (int j = 2; j < 32; ++j)
                        t[j] = fmaf(p1, t[j - 1], q1 * t[j - 2]);

                    float2* row = &tblp[(bn * BH + bh) * 16];
                    #pragma unroll
                    for (int p = 0; p < 16; ++p)
                        row[p ^ bh] = make_float2(t[p], t[p + 16]);  // ds_write_b64
                    pqs[bn * BH + bh] = pqv[bt];   // every batch (bugfix: pqs is per-batch staging)
                }
                __syncthreads();

                // ---- consume: one ds_read_b64 per n gives (ta, tb) seed ----
                const float2* rowh = &tblp[h * 16 + rdoff];
                #pragma unroll
                for (int nl = 0; nl < NB; ++nl) {
                    const float2 tab = rowh[nl * (BH * 16)];
                    const float2 pq  = pqs[nl * BH + h];
                    float ta = tab.x, tb = tab.y;
                    acc[0] += ta;
                    acc[1] += tb;
                    #pragma unroll
                    for (int k = 2; k < KL; ++k) {
                        const float tc = fmaf(pq.x, tb, pq.y * ta);
                        acc[k] += tc;
                        ta = tb; tb = tc;
                    }
                }
            }

            // ---- epilogue: LDS transpose -> float4 coalesced stores ----
            __syncthreads();
            float* scr = (float*)tblp;       // [128 l][16 h] floats = 8 KB
            #pragma unroll
            for (int k = 0; k < KL; ++k)
                scr[(sub + 16 * k) * BH + h] = acc[k];
            __syncthreads();
            const float4* scr4 = (const float4*)scr;
            float4* out4 = (float4*)out;
            #pragma unroll
            for (int i = 0; i < 2; ++i) {
                const int flat = i * 256 + tid;  // float4 index: 128 l x 4
                const int ll = flat >> 2, q = flat & 3;
                const int l = l0 + ll;
                if (l < L) out4[(size_t)l * (H_DIM / 4) + (h0 >> 2) + q] = scr4[flat];
            }
        }
        // advance start values by s^128 for the next l-segment
        if (ls + 1 < LPB) {
            #pragma unroll
            for (int bt = 0; bt < NBATCH; ++bt)
                w0v[bt] = cmul(w0v[bt], s128v[bt]);
        }
    }
}

// ---------------- generic fallback (round-1 proven structure) ----------------

#define HT 64
#define CHUNK 16

__global__ __launch_bounds__(256) void dss_kernel_fb(
    const float* __restrict__ log_dt,
    const float* __restrict__ lam_log_neg_re,
    const float* __restrict__ lam_im,
    const float* __restrict__ W,
    const int*   __restrict__ Lp,
    float* __restrict__ out,
    int H, int N)
{
    __shared__ float4 params[N_DIM * HT];
    const int tid = threadIdx.x;
    const int h0 = blockIdx.x * HT;
    const int l0_blk = blockIdx.y * 64;
    const int L = *Lp;
    const float2* __restrict__ W2 = (const float2*)W;

    for (int flat = tid; flat < N * HT; flat += 256) {
        const int hl = flat & (HT - 1);
        const int n  = flat >> 6;
        const int h  = h0 + hl;
        const float dt0 = expf(log_dt[2 * h]);
        const float dt1 = expf(log_dt[2 * h + 1]);
        const float lre = -expf(lam_log_neg_re[n]);
        const float lmi = lam_im[n];
        const float a = dt0 * lre;
        const float b = dt1 * lmi;
        const float eA = expf(a);
        float sb, cb;
        sincosf(b, &sb, &cb);
        const float em1r = eA * cb - 1.0f;
        const float em1i = eA * sb;
        const float den = fmaxf(lre * lre + lmi * lmi, 1e-14f);
        const float rr =  lre / den;
        const float ri = -lmi / den;
        const float2 wc = W2[h * N + n];
        const float trm = em1r * rr - em1i * ri;
        const float tim = em1r * ri + em1i * rr;
        params[flat] = make_float4(a, b,
                                   wc.x * trm - wc.y * tim,
                                   wc.x * tim + wc.y * trm);
    }
    __syncthreads();

    const int hl = tid & (HT - 1);
    const int chunk = tid >> 6;
    const int l0 = l0_blk + chunk * CHUNK;
    if (l0 >= L) return;

    float acc[CHUNK];
    #pragma unroll
    for (int k = 0; k < CHUNK; ++k) acc[k] = 0.0f;

    const double TWO_PI  = 6.283185307179586476925286766559;
    const double INV_2PI = 0.15915494309189533576888376337251;

    for (int n = 0; n < N; ++n) {
        const float4 pp = params[n * HT + hl];
        const float a = pp.x, b = pp.y, wr = pp.z, wi = pp.w;
        double ph = (double)b * (double)l0;
        ph -= TWO_PI * rint(ph * INV_2PI);
        const float th = (float)ph;
        const float e0 = expf(a * (float)l0);
        float s0, c0;
        sincosf(th, &s0, &c0);
        float zr = e0 * c0;
        float zi = e0 * s0;
        const float eA = expf(a);
        float sb, cb;
        sincosf(b, &sb, &cb);
        const float str = eA * cb;
        const float sti = eA * sb;
        #pragma unroll
        for (int k = 0; k < CHUNK; ++k) {
            acc[k] = fmaf(wr, zr, fmaf(-wi, zi, acc[k]));
            const float nzr = zr * str - zi * sti;
            const float nzi = fmaf(zr, sti, zi * str);
            zr = nzr; zi = nzi;
        }
    }

    #pragma unroll
    for (int k = 0; k < CHUNK; ++k) {
        const int l = l0 + k;
        if (l < L) out[(size_t)l * H + h0 + hl] = acc[k];
    }
}

// ---------------- launch ----------------

extern "C" void kernel_launch(void* const* d_in, const int* in_sizes, int n_in,
                              void* d_out, int out_size, void* d_ws, size_t ws_size,
                              hipStream_t stream) {
    const float* log_dt = (const float*)d_in[0];
    const float* llnr   = (const float*)d_in[1];
    const float* lim    = (const float*)d_in[2];
    const float* W      = (const float*)d_in[3];
    const int*   Lp     = (const int*)d_in[4];

    const int H = in_sizes[0] / 2;
    const int N = in_sizes[1];
    const int L = out_size / (H > 0 ? H : 1);

    if (H == H_DIM && N == N_DIM && L <= LPB * 8 * BL) {
        const int lsegs = (L + BL - 1) / BL;
        const int gpairs = (lsegs + LPB - 1) / LPB;
        dim3 grid(H_DIM / BH, gpairs);
        dss_fused<<<grid, 256, 0, stream>>>(log_dt, llnr, lim, W, Lp, (float*)d_out);
    } else {
        dim3 grid((H + HT - 1) / HT, (L + 63) / 64);
        dss_kernel_fb<<<grid, 256, 0, stream>>>(log_dt, llnr, lim, W, Lp,
                                                (float*)d_out, H, N);
    }
}